// Round 1
// baseline (415.919 us; speedup 1.0000x reference)
//
#include <hip/hip_runtime.h>
#include <math.h>

#define B_ 32
#define T_ 1024
#define D_ 512
#define U_ 64
#define TS_ 4          // t-reduction split in K1
#define TH_ (T_/TS_)   // 256
#define TC_ 32         // K1 t-chunk staged in LDS
#define SR_ 10.0f
#define EPS_ 1e-7f

// ---------------------------------------------------------------------------
// K1: partial combined matrices. For each (b, d-tile of 64, t-quarter):
//   P[ts][b][0][d][u] += sum_t x1*w3 + x2*w2   (M1 part)
//   P[ts][b][1][d][u] += sum_t x1*w2 + x2*w3   (M2 part)
// NOTE: accumulation kept as SEPARATE statements so each contracts to v_fma
// (a += x*y + z*w forces mul+fma+add = 1.5x VALU — measured R2 regression).
// ---------------------------------------------------------------------------
__global__ __launch_bounds__(256, 4) void k1_partials(
    const float* __restrict__ x1, const float* __restrict__ x2,
    const float* __restrict__ w2, const float* __restrict__ w3,
    float* __restrict__ P)
{
    __shared__ float x1s[TC_*64];
    __shared__ float x2s[TC_*64];
    __shared__ float w2s[TC_*64];
    __shared__ float w3s[TC_*64];

    const int dt  = blockIdx.x;       // 0..7
    const int ts  = blockIdx.y;       // 0..TS_-1
    const int b   = blockIdx.z;       // 0..31
    const int d0  = dt * 64;
    const int tid = threadIdx.x;
    const int td  = tid & 15;         // d = d0 + td*4 + i
    const int tu  = tid >> 4;         // u = tu*4 + j

    float accM1[4][4];
    float accM2[4][4];
    #pragma unroll
    for (int i = 0; i < 4; ++i)
        #pragma unroll
        for (int j = 0; j < 4; ++j) { accM1[i][j] = 0.f; accM2[i][j] = 0.f; }

    const size_t xb = (size_t)b * T_ * D_;

    for (int c = 0; c < TH_/TC_; ++c) {
        const int tb = ts*TH_ + c*TC_;
        #pragma unroll
        for (int j = 0; j < 2; ++j) {
            int l  = j*256 + tid;           // 0..511
            int tl = l >> 4;                // 0..31
            int f  = (l & 15) << 2;         // 0..60
            *(float4*)&x1s[tl*64 + f] = *(const float4*)&x1[xb + (size_t)(tb+tl)*D_ + d0 + f];
            *(float4*)&x2s[tl*64 + f] = *(const float4*)&x2[xb + (size_t)(tb+tl)*D_ + d0 + f];
            *(float4*)&w2s[tl*64 + f] = *(const float4*)&w2[(size_t)(tb+tl)*U_ + f];
            *(float4*)&w3s[tl*64 + f] = *(const float4*)&w3[(size_t)(tb+tl)*U_ + f];
        }
        __syncthreads();
        #pragma unroll 4
        for (int t = 0; t < TC_; ++t) {
            float4 a1 = *(const float4*)&x1s[t*64 + td*4];
            float4 a2 = *(const float4*)&x2s[t*64 + td*4];
            float4 c2 = *(const float4*)&w2s[t*64 + tu*4];
            float4 c3 = *(const float4*)&w3s[t*64 + tu*4];
            float a1v[4] = {a1.x,a1.y,a1.z,a1.w};
            float a2v[4] = {a2.x,a2.y,a2.z,a2.w};
            float c2v[4] = {c2.x,c2.y,c2.z,c2.w};
            float c3v[4] = {c3.x,c3.y,c3.z,c3.w};
            #pragma unroll
            for (int i = 0; i < 4; ++i)
                #pragma unroll
                for (int j = 0; j < 4; ++j) {
                    accM1[i][j] += a1v[i]*c3v[j];
                    accM1[i][j] += a2v[i]*c2v[j];
                    accM2[i][j] += a1v[i]*c2v[j];
                    accM2[i][j] += a2v[i]*c3v[j];
                }
        }
        __syncthreads();
    }

    const size_t DU = (size_t)D_ * U_;
    #pragma unroll
    for (int i = 0; i < 4; ++i) {
        size_t base = (((size_t)ts*B_ + b)*2)*DU + (size_t)(d0 + td*4 + i)*U_ + tu*4;
        float4 v1 = {accM1[i][0], accM1[i][1], accM1[i][2], accM1[i][3]};
        float4 v2 = {accM2[i][0], accM2[i][1], accM2[i][2], accM2[i][3]};
        *(float4*)&P[base]      = v1;
        *(float4*)&P[base + DU] = v2;
    }
}

// ---------------------------------------------------------------------------
// K1b: M1 = w1 + sum_ts P[ts][b][0];  M2 = w1 + sum_ts P[ts][b][1]
// ---------------------------------------------------------------------------
__global__ __launch_bounds__(256) void k1_combine(
    const float* __restrict__ P, const float* __restrict__ w1,
    float* __restrict__ M1, float* __restrict__ M2)
{
    const int n = blockIdx.x*256 + threadIdx.x;   // 0 .. B*D*U/4-1
    const int b = n >> 13;                        // D*U/4 = 8192
    const int r = n & 8191;
    const size_t du = (size_t)r * 4;
    const size_t DU = (size_t)D_ * U_;
    float4 w = *(const float4*)&w1[du];
    float4 s1 = w, s2 = w;
    #pragma unroll
    for (int ts = 0; ts < TS_; ++ts) {
        const float* Pb = P + (((size_t)ts*B_ + b)*2)*DU + du;
        float4 a = *(const float4*)&Pb[0];
        float4 c = *(const float4*)&Pb[DU];
        s1.x += a.x; s1.y += a.y; s1.z += a.z; s1.w += a.w;
        s2.x += c.x; s2.y += c.y; s2.z += c.z; s2.w += c.w;
    }
    *(float4*)&M1[(size_t)b*DU + du] = s1;
    *(float4*)&M2[(size_t)b*DU + du] = s2;
}

// ---------------------------------------------------------------------------
// K2: eij[br][b][t] = SR * sum_u tanh( sum_d x[b,t,d]*M[b,d,u] ) * we[u]
// block: (t-tile 64) x (b) x (branch); 256 threads; ~38 KiB LDS -> 4 blk/CU
// ---------------------------------------------------------------------------
#define TT_ 64
#define XPAD_ 69
__global__ __launch_bounds__(256, 4) void k2_eij(
    const float* __restrict__ x1, const float* __restrict__ x2,
    const float* __restrict__ M1, const float* __restrict__ M2,
    const float* __restrict__ we, float* __restrict__ eij)
{
    __shared__ float xT[64*XPAD_];   // [d][t] transposed, padded
    __shared__ float Ms[64*64];      // [d][u]
    __shared__ float wes[64];
    __shared__ float red[16*TT_];

    const int tt = blockIdx.x;       // 0..15
    const int b  = blockIdx.y;       // 0..31
    const int br = blockIdx.z;       // 0..1
    const float* x = br ? x2 : x1;
    const float* M = (br ? M2 : M1) + (size_t)b * D_ * U_;
    const int tid = threadIdx.x;
    const int tdl = tid & 15;        // t = tdl*4 + i
    const int tu  = tid >> 4;        // u = tu*4 + j
    if (tid < 64) wes[tid] = we[tid];

    float acc[4][4];
    #pragma unroll
    for (int i = 0; i < 4; ++i)
        #pragma unroll
        for (int j = 0; j < 4; ++j) acc[i][j] = 0.f;

    const size_t xb = (size_t)b*T_*D_ + (size_t)tt*TT_*D_;

    for (int c = 0; c < D_/64; ++c) {
        #pragma unroll
        for (int j = 0; j < 4; ++j) {
            int l  = j*256 + tid;        // 0..1023
            int tl = l >> 4;             // 0..63
            int f  = (l & 15) << 2;      // 0..60
            float4 v = *(const float4*)&x[xb + (size_t)tl*D_ + c*64 + f];
            xT[(f+0)*XPAD_ + tl] = v.x;
            xT[(f+1)*XPAD_ + tl] = v.y;
            xT[(f+2)*XPAD_ + tl] = v.z;
            xT[(f+3)*XPAD_ + tl] = v.w;
        }
        #pragma unroll
        for (int j = 0; j < 4; ++j) {
            int l  = j*256 + tid;
            int dl = l >> 4;
            int f  = (l & 15) << 2;
            *(float4*)&Ms[dl*64 + f] = *(const float4*)&M[(size_t)(c*64 + dl)*U_ + f];
        }
        __syncthreads();
        #pragma unroll 4
        for (int d = 0; d < 64; ++d) {
            float4 xv = *(const float4*)&xT[d*XPAD_ + tdl*4];
            float4 mv = *(const float4*)&Ms[d*64 + tu*4];
            float xvv[4] = {xv.x,xv.y,xv.z,xv.w};
            float mvv[4] = {mv.x,mv.y,mv.z,mv.w};
            #pragma unroll
            for (int i = 0; i < 4; ++i)
                #pragma unroll
                for (int j = 0; j < 4; ++j)
                    acc[i][j] += xvv[i]*mvv[j];
        }
        __syncthreads();
    }

    #pragma unroll
    for (int i = 0; i < 4; ++i) {
        float p = 0.f;
        #pragma unroll
        for (int j = 0; j < 4; ++j)
            p += tanhf(acc[i][j]) * wes[tu*4 + j];
        red[tu*TT_ + tdl*4 + i] = p;
    }
    __syncthreads();
    if (tid < TT_) {
        float s = 0.f;
        #pragma unroll
        for (int q = 0; q < 16; ++q) s += red[q*TT_ + tid];
        eij[((size_t)br*B_ + b)*T_ + tt*TT_ + tid] = SR_ * s;
    }
}

// ---------------------------------------------------------------------------
// K45: fused softmax + scale. Each block redundantly computes the softmax
// normalization for its (br,b) slab (4 KB of eij), then scales a 64-t chunk.
//   ww = exp(e-m)/(sum + eps*exp(-m));  out[br][b,t,d] = x[b,t,d]*ww[t]
// ---------------------------------------------------------------------------
__global__ __launch_bounds__(256) void k45_scale(
    const float* __restrict__ x1, const float* __restrict__ x2,
    const float* __restrict__ eij, float* __restrict__ out)
{
    __shared__ float sdata[256];
    __shared__ float wws[T_];

    const int tt = blockIdx.x;       // 0..15 : t-chunk of 64
    const int b  = blockIdx.y;       // 0..31
    const int br = blockIdx.z;       // 0..1
    const int tid = threadIdx.x;
    const float* e = eij + ((size_t)br*B_ + b) * T_;

    float v[4];
    float m = -1e30f;
    #pragma unroll
    for (int i = 0; i < 4; ++i) { v[i] = e[tid + i*256]; m = fmaxf(m, v[i]); }
    sdata[tid] = m; __syncthreads();
    for (int s = 128; s > 0; s >>= 1) {
        if (tid < s) sdata[tid] = fmaxf(sdata[tid], sdata[tid+s]);
        __syncthreads();
    }
    m = sdata[0]; __syncthreads();
    float ssum = 0.f;
    #pragma unroll
    for (int i = 0; i < 4; ++i) { v[i] = expf(v[i] - m); ssum += v[i]; }
    sdata[tid] = ssum; __syncthreads();
    for (int s = 128; s > 0; s >>= 1) {
        if (tid < s) sdata[tid] += sdata[tid+s];
        __syncthreads();
    }
    const float inv = 1.0f / (sdata[0] + EPS_ * expf(-m));
    #pragma unroll
    for (int i = 0; i < 4; ++i) wws[tid + i*256] = v[i] * inv;
    __syncthreads();

    // scale: t in [tt*64, tt*64+64), all d. 64*128 float4 = 8192; 32/thread.
    const float* x = br ? x2 : x1;
    const size_t xb4 = ((size_t)b*T_ + (size_t)tt*64) * (D_/4);
    float* o = out + (size_t)br*B_*T_*D_;
    #pragma unroll
    for (int k = 0; k < 32; ++k) {
        int idx = k*256 + tid;           // 0..8191
        int tl  = idx >> 7;              // 0..63 (128 float4 per t-row)
        float w = wws[tt*64 + tl];
        float4 xv = ((const float4*)x)[xb4 + idx];
        float4 ov = {xv.x*w, xv.y*w, xv.z*w, xv.w*w};
        ((float4*)o)[xb4 + idx] = ov;
    }
}

// ---------------------------------------------------------------------------
extern "C" void kernel_launch(void* const* d_in, const int* in_sizes, int n_in,
                              void* d_out, int out_size, void* d_ws, size_t ws_size,
                              hipStream_t stream)
{
    const float* x1 = (const float*)d_in[0];
    const float* x2 = (const float*)d_in[1];
    const float* w1 = (const float*)d_in[2];
    const float* w2 = (const float*)d_in[3];
    const float* w3 = (const float*)d_in[4];
    const float* we = (const float*)d_in[5];
    float* out = (float*)d_out;
    float* ws  = (float*)d_ws;

    // workspace layout (floats)
    float* P   = ws;                             // TS_*B_*2*D_*U_ = 8,388,608
    float* M1  = P   + (size_t)TS_*B_*2*D_*U_;   // 1,048,576
    float* M2  = M1  + (size_t)B_*D_*U_;         // 1,048,576
    float* eij = M2  + (size_t)B_*D_*U_;         // 65,536

    k1_partials<<<dim3(8, TS_, B_), 256, 0, stream>>>(x1, x2, w2, w3, P);
    k1_combine <<<dim3((B_*D_*U_/4 + 255)/256), 256, 0, stream>>>(P, w1, M1, M2);
    k2_eij     <<<dim3(T_/TT_, B_, 2), 256, 0, stream>>>(x1, x2, M1, M2, we, eij);
    k45_scale  <<<dim3(16, B_, 2), 256, 0, stream>>>(x1, x2, eij, out);
}

// Round 2
// 373.421 us; speedup vs baseline: 1.1138x; 1.1138x over previous
//
#include <hip/hip_runtime.h>
#include <math.h>

#define B_ 32
#define T_ 1024
#define D_ 512
#define U_ 64
#define TS_ 4          // t-reduction split in K1
#define TH_ (T_/TS_)   // 256
#define TC_ 32         // K1 t-chunk staged in LDS
#define SR_ 10.0f
#define EPS_ 1e-7f

typedef __attribute__((ext_vector_type(8))) short bf16x8;
typedef __attribute__((ext_vector_type(4))) float f32x4;

#define LSTRIDE 40     // ushorts per LDS row: 32 t + 8 pad; 80 B rows keep b128 reads 16B-aligned

// ---------------------------------------------------------------------------
// K1 (MFMA): per (b, d-tile 64, t-quarter) compute
//   P[ts][b][0][d][u] += sum_t x1*w3 + x2*w2   (M1 part)
//   P[ts][b][1][d][u] += sum_t x1*w2 + x2*w3   (M2 part)
// as GEMMs on v_mfma_f32_16x16x32_bf16 with 2-term bf16 split emulation:
//   x = hi + lo (truncated bf16), x*w ~= xh*wh + xh*wl + xl*wh  (residual ~2^-16)
// Staging: lane->feature column, iterate t: global reads stay coalesced,
// split+pack t-pairs, ds_write_b32 into [feat][t] bf16 tiles (no transpose pass).
// A/B frags: lane holds row/col = lane&15, 8 contiguous k at k0=8*(lane>>4);
// identical k-bijection on A and B makes the k-order assumption self-canceling.
// C/D layout (m89-verified): col = lane&15, row = (lane>>4)*4 + reg.
// ---------------------------------------------------------------------------
__global__ __launch_bounds__(256, 3) void k1_partials(
    const float* __restrict__ x1, const float* __restrict__ x2,
    const float* __restrict__ w2, const float* __restrict__ w3,
    float* __restrict__ P)
{
    __shared__ ushort lds[8][64*LSTRIDE];  // x1h,x1l,x2h,x2l,w2h,w2l,w3h,w3l (40 KiB)

    const int dt  = blockIdx.x;       // 0..7
    const int ts  = blockIdx.y;       // 0..TS_-1
    const int b   = blockIdx.z;       // 0..31
    const int d0  = dt * 64;
    const int tid = threadIdx.x;
    const int lane = tid & 63;
    const int wid  = tid >> 6;        // 0..3
    const int wd   = wid & 1;         // d-half (32 rows)
    const int wu   = wid >> 1;        // u-half (32 cols)
    const int lr   = lane & 15;       // frag row/col within 16
    const int lg   = lane >> 4;       // k-group 0..3
    const int col  = tid & 63;        // staging feature column
    const int tq   = tid >> 6;        // staging t-subrange (8 t each)

    f32x4 acc1[2][2], acc2[2][2];
    const f32x4 z = {0.f, 0.f, 0.f, 0.f};
    #pragma unroll
    for (int mi = 0; mi < 2; ++mi)
        #pragma unroll
        for (int ni = 0; ni < 2; ++ni) { acc1[mi][ni] = z; acc2[mi][ni] = z; }

    const size_t xb = (size_t)b * T_ * D_;

    for (int c = 0; c < TH_/TC_; ++c) {
        const int tb = ts*TH_ + c*TC_ + 8*tq;   // this thread's t base (8 rows)
        // ---- stage + split: 4 arrays x 8 t-rows per thread, coalesced reads
        const float* ga[4] = { x1 + xb + (size_t)tb*D_ + d0 + col,
                               x2 + xb + (size_t)tb*D_ + d0 + col,
                               w2 + (size_t)tb*U_ + col,
                               w3 + (size_t)tb*U_ + col };
        const int stra[4] = { D_, D_, U_, U_ };
        #pragma unroll
        for (int a = 0; a < 4; ++a) {
            float v[8];
            #pragma unroll
            for (int j = 0; j < 8; ++j) v[j] = ga[a][(size_t)j * stra[a]];
            uint* hb = (uint*)lds[a*2];
            uint* lb = (uint*)lds[a*2+1];
            #pragma unroll
            for (int p = 0; p < 4; ++p) {
                float e = v[2*p], o = v[2*p+1];
                uint ue = __float_as_uint(e), uo = __float_as_uint(o);
                uint he = ue & 0xffff0000u, ho = uo & 0xffff0000u;
                float le = e - __uint_as_float(he);
                float lo = o - __uint_as_float(ho);
                int idx = col*(LSTRIDE/2) + 4*tq + p;   // uint units
                hb[idx] = (he >> 16) | ho;
                lb[idx] = (__float_as_uint(le) >> 16) | (__float_as_uint(lo) & 0xffff0000u);
            }
        }
        __syncthreads();
        // ---- fragment loads (ds_read_b128, 16B-aligned)
        bf16x8 A1h[2], A1l[2], A2h[2], A2l[2];
        bf16x8 B2h[2], B2l[2], B3h[2], B3l[2];
        #pragma unroll
        for (int mi = 0; mi < 2; ++mi) {
            int off = (32*wd + 16*mi + lr)*LSTRIDE + 8*lg;
            A1h[mi] = *(const bf16x8*)&lds[0][off];
            A1l[mi] = *(const bf16x8*)&lds[1][off];
            A2h[mi] = *(const bf16x8*)&lds[2][off];
            A2l[mi] = *(const bf16x8*)&lds[3][off];
        }
        #pragma unroll
        for (int ni = 0; ni < 2; ++ni) {
            int off = (32*wu + 16*ni + lr)*LSTRIDE + 8*lg;
            B2h[ni] = *(const bf16x8*)&lds[4][off];
            B2l[ni] = *(const bf16x8*)&lds[5][off];
            B3h[ni] = *(const bf16x8*)&lds[6][off];
            B3l[ni] = *(const bf16x8*)&lds[7][off];
        }
        // ---- MFMA: 48 per wave per chunk
        #pragma unroll
        for (int mi = 0; mi < 2; ++mi)
            #pragma unroll
            for (int ni = 0; ni < 2; ++ni) {
                f32x4 c1 = acc1[mi][ni];
                f32x4 c2 = acc2[mi][ni];
                c1 = __builtin_amdgcn_mfma_f32_16x16x32_bf16(A1h[mi], B3h[ni], c1, 0, 0, 0);
                c1 = __builtin_amdgcn_mfma_f32_16x16x32_bf16(A1h[mi], B3l[ni], c1, 0, 0, 0);
                c1 = __builtin_amdgcn_mfma_f32_16x16x32_bf16(A1l[mi], B3h[ni], c1, 0, 0, 0);
                c1 = __builtin_amdgcn_mfma_f32_16x16x32_bf16(A2h[mi], B2h[ni], c1, 0, 0, 0);
                c1 = __builtin_amdgcn_mfma_f32_16x16x32_bf16(A2h[mi], B2l[ni], c1, 0, 0, 0);
                c1 = __builtin_amdgcn_mfma_f32_16x16x32_bf16(A2l[mi], B2h[ni], c1, 0, 0, 0);
                c2 = __builtin_amdgcn_mfma_f32_16x16x32_bf16(A1h[mi], B2h[ni], c2, 0, 0, 0);
                c2 = __builtin_amdgcn_mfma_f32_16x16x32_bf16(A1h[mi], B2l[ni], c2, 0, 0, 0);
                c2 = __builtin_amdgcn_mfma_f32_16x16x32_bf16(A1l[mi], B2h[ni], c2, 0, 0, 0);
                c2 = __builtin_amdgcn_mfma_f32_16x16x32_bf16(A2h[mi], B3h[ni], c2, 0, 0, 0);
                c2 = __builtin_amdgcn_mfma_f32_16x16x32_bf16(A2h[mi], B3l[ni], c2, 0, 0, 0);
                c2 = __builtin_amdgcn_mfma_f32_16x16x32_bf16(A2l[mi], B3h[ni], c2, 0, 0, 0);
                acc1[mi][ni] = c1;
                acc2[mi][ni] = c2;
            }
        __syncthreads();
    }

    // ---- epilogue: C/D layout col=lane&15, row=(lane>>4)*4+reg
    const size_t DU = (size_t)D_ * U_;
    const size_t base0 = (((size_t)ts*B_ + b)*2)*DU;
    #pragma unroll
    for (int mi = 0; mi < 2; ++mi)
        #pragma unroll
        for (int ni = 0; ni < 2; ++ni) {
            const int d = d0 + 32*wd + 16*mi + 4*lg;
            const int u = 32*wu + 16*ni + lr;
            #pragma unroll
            for (int r = 0; r < 4; ++r) {
                P[base0 + (size_t)(d+r)*U_ + u]      = acc1[mi][ni][r];
                P[base0 + DU + (size_t)(d+r)*U_ + u] = acc2[mi][ni][r];
            }
        }
}

// ---------------------------------------------------------------------------
// K1b: M1 = w1 + sum_ts P[ts][b][0];  M2 = w1 + sum_ts P[ts][b][1]
// ---------------------------------------------------------------------------
__global__ __launch_bounds__(256) void k1_combine(
    const float* __restrict__ P, const float* __restrict__ w1,
    float* __restrict__ M1, float* __restrict__ M2)
{
    const int n = blockIdx.x*256 + threadIdx.x;   // 0 .. B*D*U/4-1
    const int b = n >> 13;                        // D*U/4 = 8192
    const int r = n & 8191;
    const size_t du = (size_t)r * 4;
    const size_t DU = (size_t)D_ * U_;
    float4 w = *(const float4*)&w1[du];
    float4 s1 = w, s2 = w;
    #pragma unroll
    for (int ts = 0; ts < TS_; ++ts) {
        const float* Pb = P + (((size_t)ts*B_ + b)*2)*DU + du;
        float4 a = *(const float4*)&Pb[0];
        float4 c = *(const float4*)&Pb[DU];
        s1.x += a.x; s1.y += a.y; s1.z += a.z; s1.w += a.w;
        s2.x += c.x; s2.y += c.y; s2.z += c.z; s2.w += c.w;
    }
    *(float4*)&M1[(size_t)b*DU + du] = s1;
    *(float4*)&M2[(size_t)b*DU + du] = s2;
}

// ---------------------------------------------------------------------------
// K2: eij[br][b][t] = SR * sum_u tanh( sum_d x[b,t,d]*M[b,d,u] ) * we[u]
// block: (t-tile 64) x (b) x (branch); 256 threads; ~38 KiB LDS -> 4 blk/CU
// ---------------------------------------------------------------------------
#define TT_ 64
#define XPAD_ 69
__global__ __launch_bounds__(256, 4) void k2_eij(
    const float* __restrict__ x1, const float* __restrict__ x2,
    const float* __restrict__ M1, const float* __restrict__ M2,
    const float* __restrict__ we, float* __restrict__ eij)
{
    __shared__ float xT[64*XPAD_];   // [d][t] transposed, padded
    __shared__ float Ms[64*64];      // [d][u]
    __shared__ float wes[64];
    __shared__ float red[16*TT_];

    const int tt = blockIdx.x;       // 0..15
    const int b  = blockIdx.y;       // 0..31
    const int br = blockIdx.z;       // 0..1
    const float* x = br ? x2 : x1;
    const float* M = (br ? M2 : M1) + (size_t)b * D_ * U_;
    const int tid = threadIdx.x;
    const int tdl = tid & 15;        // t = tdl*4 + i
    const int tu  = tid >> 4;        // u = tu*4 + j
    if (tid < 64) wes[tid] = we[tid];

    float acc[4][4];
    #pragma unroll
    for (int i = 0; i < 4; ++i)
        #pragma unroll
        for (int j = 0; j < 4; ++j) acc[i][j] = 0.f;

    const size_t xb = (size_t)b*T_*D_ + (size_t)tt*TT_*D_;

    for (int c = 0; c < D_/64; ++c) {
        #pragma unroll
        for (int j = 0; j < 4; ++j) {
            int l  = j*256 + tid;        // 0..1023
            int tl = l >> 4;             // 0..63
            int f  = (l & 15) << 2;      // 0..60
            float4 v = *(const float4*)&x[xb + (size_t)tl*D_ + c*64 + f];
            xT[(f+0)*XPAD_ + tl] = v.x;
            xT[(f+1)*XPAD_ + tl] = v.y;
            xT[(f+2)*XPAD_ + tl] = v.z;
            xT[(f+3)*XPAD_ + tl] = v.w;
        }
        #pragma unroll
        for (int j = 0; j < 4; ++j) {
            int l  = j*256 + tid;
            int dl = l >> 4;
            int f  = (l & 15) << 2;
            *(float4*)&Ms[dl*64 + f] = *(const float4*)&M[(size_t)(c*64 + dl)*U_ + f];
        }
        __syncthreads();
        #pragma unroll 4
        for (int d = 0; d < 64; ++d) {
            float4 xv = *(const float4*)&xT[d*XPAD_ + tdl*4];
            float4 mv = *(const float4*)&Ms[d*64 + tu*4];
            float xvv[4] = {xv.x,xv.y,xv.z,xv.w};
            float mvv[4] = {mv.x,mv.y,mv.z,mv.w};
            #pragma unroll
            for (int i = 0; i < 4; ++i)
                #pragma unroll
                for (int j = 0; j < 4; ++j)
                    acc[i][j] += xvv[i]*mvv[j];
        }
        __syncthreads();
    }

    #pragma unroll
    for (int i = 0; i < 4; ++i) {
        float p = 0.f;
        #pragma unroll
        for (int j = 0; j < 4; ++j)
            p += tanhf(acc[i][j]) * wes[tu*4 + j];
        red[tu*TT_ + tdl*4 + i] = p;
    }
    __syncthreads();
    if (tid < TT_) {
        float s = 0.f;
        #pragma unroll
        for (int q = 0; q < 16; ++q) s += red[q*TT_ + tid];
        eij[((size_t)br*B_ + b)*T_ + tt*TT_ + tid] = SR_ * s;
    }
}

// ---------------------------------------------------------------------------
// K45: fused softmax + scale. Each block redundantly computes the softmax
// normalization for its (br,b) slab (4 KB of eij), then scales a 64-t chunk.
//   ww = exp(e-m)/(sum + eps*exp(-m));  out[br][b,t,d] = x[b,t,d]*ww[t]
// ---------------------------------------------------------------------------
__global__ __launch_bounds__(256) void k45_scale(
    const float* __restrict__ x1, const float* __restrict__ x2,
    const float* __restrict__ eij, float* __restrict__ out)
{
    __shared__ float sdata[256];
    __shared__ float wws[T_];

    const int tt = blockIdx.x;       // 0..15 : t-chunk of 64
    const int b  = blockIdx.y;       // 0..31
    const int br = blockIdx.z;       // 0..1
    const int tid = threadIdx.x;
    const float* e = eij + ((size_t)br*B_ + b) * T_;

    float v[4];
    float m = -1e30f;
    #pragma unroll
    for (int i = 0; i < 4; ++i) { v[i] = e[tid + i*256]; m = fmaxf(m, v[i]); }
    sdata[tid] = m; __syncthreads();
    for (int s = 128; s > 0; s >>= 1) {
        if (tid < s) sdata[tid] = fmaxf(sdata[tid], sdata[tid+s]);
        __syncthreads();
    }
    m = sdata[0]; __syncthreads();
    float ssum = 0.f;
    #pragma unroll
    for (int i = 0; i < 4; ++i) { v[i] = expf(v[i] - m); ssum += v[i]; }
    sdata[tid] = ssum; __syncthreads();
    for (int s = 128; s > 0; s >>= 1) {
        if (tid < s) sdata[tid] += sdata[tid+s];
        __syncthreads();
    }
    const float inv = 1.0f / (sdata[0] + EPS_ * expf(-m));
    #pragma unroll
    for (int i = 0; i < 4; ++i) wws[tid + i*256] = v[i] * inv;
    __syncthreads();

    // scale: t in [tt*64, tt*64+64), all d. 64*128 float4 = 8192; 32/thread.
    const float* x = br ? x2 : x1;
    const size_t xb4 = ((size_t)b*T_ + (size_t)tt*64) * (D_/4);
    float* o = out + (size_t)br*B_*T_*D_;
    #pragma unroll
    for (int k = 0; k < 32; ++k) {
        int idx = k*256 + tid;           // 0..8191
        int tl  = idx >> 7;              // 0..63 (128 float4 per t-row)
        float w = wws[tt*64 + tl];
        float4 xv = ((const float4*)x)[xb4 + idx];
        float4 ov = {xv.x*w, xv.y*w, xv.z*w, xv.w*w};
        ((float4*)o)[xb4 + idx] = ov;
    }
}

// ---------------------------------------------------------------------------
extern "C" void kernel_launch(void* const* d_in, const int* in_sizes, int n_in,
                              void* d_out, int out_size, void* d_ws, size_t ws_size,
                              hipStream_t stream)
{
    const float* x1 = (const float*)d_in[0];
    const float* x2 = (const float*)d_in[1];
    const float* w1 = (const float*)d_in[2];
    const float* w2 = (const float*)d_in[3];
    const float* w3 = (const float*)d_in[4];
    const float* we = (const float*)d_in[5];
    float* out = (float*)d_out;
    float* ws  = (float*)d_ws;

    // workspace layout (floats)
    float* P   = ws;                             // TS_*B_*2*D_*U_ = 8,388,608
    float* M1  = P   + (size_t)TS_*B_*2*D_*U_;   // 1,048,576
    float* M2  = M1  + (size_t)B_*D_*U_;         // 1,048,576
    float* eij = M2  + (size_t)B_*D_*U_;         // 65,536

    k1_partials<<<dim3(8, TS_, B_), 256, 0, stream>>>(x1, x2, w2, w3, P);
    k1_combine <<<dim3((B_*D_*U_/4 + 255)/256), 256, 0, stream>>>(P, w1, M1, M2);
    k2_eij     <<<dim3(T_/TT_, B_, 2), 256, 0, stream>>>(x1, x2, M1, M2, we, eij);
    k45_scale  <<<dim3(16, B_, 2), 256, 0, stream>>>(x1, x2, eij, out);
}

// Round 4
// 317.368 us; speedup vs baseline: 1.3105x; 1.1766x over previous
//
#include <hip/hip_runtime.h>
#include <math.h>

#define B_ 32
#define T_ 1024
#define D_ 512
#define U_ 64
#define TS_ 4          // t-reduction split in K1
#define TH_ (T_/TS_)   // 256
#define TC_ 32         // K1 t-chunk staged in LDS
#define TT_ 64         // K2 t-tile
#define SR_ 10.0f
#define EPS_ 1e-7f

typedef __attribute__((ext_vector_type(8))) short bf16x8;
typedef __attribute__((ext_vector_type(4))) float f32x4;

#define LSTRIDE 40     // ushorts per LDS row: 32 t + 8 pad; 80 B rows keep b128 reads 16B-aligned

__device__ __forceinline__ uint pack_hi2(float e, float o) {
    return (__float_as_uint(e) >> 16) | (__float_as_uint(o) & 0xffff0000u);
}
__device__ __forceinline__ float hi_part(float v) {
    return __uint_as_float(__float_as_uint(v) & 0xffff0000u);
}

// ---------------------------------------------------------------------------
// K1 (MFMA): per (b, d-tile 64, t-quarter) compute
//   P[ts][b][0][d][u] += sum_t x1*w3 + x2*w2   (M1 part)
//   P[ts][b][1][d][u] += sum_t x1*w2 + x2*w3   (M2 part)
// as GEMMs on v_mfma_f32_16x16x32_bf16 with 2-term bf16 split emulation:
//   x = hi + lo (truncated bf16), x*w ~= xh*wh + xh*wl + xl*wh  (residual ~2^-16)
// Staging: lane->feature column, iterate t: global reads stay coalesced,
// split+pack t-pairs, ds_write_b32 into [feat][t] bf16 tiles (no transpose pass).
// A/B frags: lane holds row/col = lane&15, 8 contiguous k at k0=8*(lane>>4);
// identical k-bijection on A and B makes the k-order assumption self-canceling.
// C/D layout (m89-verified): col = lane&15, row = (lane>>4)*4 + reg.
// ---------------------------------------------------------------------------
__global__ __launch_bounds__(256, 3) void k1_partials(
    const float* __restrict__ x1, const float* __restrict__ x2,
    const float* __restrict__ w2, const float* __restrict__ w3,
    float* __restrict__ P)
{
    __shared__ ushort lds[8][64*LSTRIDE];  // x1h,x1l,x2h,x2l,w2h,w2l,w3h,w3l (40 KiB)

    const int dt  = blockIdx.x;       // 0..7
    const int ts  = blockIdx.y;       // 0..TS_-1
    const int b   = blockIdx.z;       // 0..31
    const int d0  = dt * 64;
    const int tid = threadIdx.x;
    const int lane = tid & 63;
    const int wid  = tid >> 6;        // 0..3
    const int wd   = wid & 1;         // d-half (32 rows)
    const int wu   = wid >> 1;        // u-half (32 cols)
    const int lr   = lane & 15;       // frag row/col within 16
    const int lg   = lane >> 4;       // k-group 0..3
    const int col  = tid & 63;        // staging feature column
    const int tq   = tid >> 6;        // staging t-subrange (8 t each)

    f32x4 acc1[2][2], acc2[2][2];
    const f32x4 z = {0.f, 0.f, 0.f, 0.f};
    #pragma unroll
    for (int mi = 0; mi < 2; ++mi)
        #pragma unroll
        for (int ni = 0; ni < 2; ++ni) { acc1[mi][ni] = z; acc2[mi][ni] = z; }

    const size_t xb = (size_t)b * T_ * D_;

    for (int c = 0; c < TH_/TC_; ++c) {
        const int tb = ts*TH_ + c*TC_ + 8*tq;   // this thread's t base (8 rows)
        // ---- stage + split: 4 arrays x 8 t-rows per thread, coalesced reads
        const float* ga[4] = { x1 + xb + (size_t)tb*D_ + d0 + col,
                               x2 + xb + (size_t)tb*D_ + d0 + col,
                               w2 + (size_t)tb*U_ + col,
                               w3 + (size_t)tb*U_ + col };
        const int stra[4] = { D_, D_, U_, U_ };
        #pragma unroll
        for (int a = 0; a < 4; ++a) {
            float v[8];
            #pragma unroll
            for (int j = 0; j < 8; ++j) v[j] = ga[a][(size_t)j * stra[a]];
            uint* hb = (uint*)lds[a*2];
            uint* lb = (uint*)lds[a*2+1];
            #pragma unroll
            for (int p = 0; p < 4; ++p) {
                float e = v[2*p], o = v[2*p+1];
                uint he = __float_as_uint(e) & 0xffff0000u;
                uint ho = __float_as_uint(o) & 0xffff0000u;
                float le = e - __uint_as_float(he);
                float lo = o - __uint_as_float(ho);
                int idx = col*(LSTRIDE/2) + 4*tq + p;   // uint units
                hb[idx] = (he >> 16) | ho;
                lb[idx] = (__float_as_uint(le) >> 16) | (__float_as_uint(lo) & 0xffff0000u);
            }
        }
        __syncthreads();
        // ---- fragment loads (ds_read_b128, 16B-aligned)
        bf16x8 A1h[2], A1l[2], A2h[2], A2l[2];
        bf16x8 B2h[2], B2l[2], B3h[2], B3l[2];
        #pragma unroll
        for (int mi = 0; mi < 2; ++mi) {
            int off = (32*wd + 16*mi + lr)*LSTRIDE + 8*lg;
            A1h[mi] = *(const bf16x8*)&lds[0][off];
            A1l[mi] = *(const bf16x8*)&lds[1][off];
            A2h[mi] = *(const bf16x8*)&lds[2][off];
            A2l[mi] = *(const bf16x8*)&lds[3][off];
        }
        #pragma unroll
        for (int ni = 0; ni < 2; ++ni) {
            int off = (32*wu + 16*ni + lr)*LSTRIDE + 8*lg;
            B2h[ni] = *(const bf16x8*)&lds[4][off];
            B2l[ni] = *(const bf16x8*)&lds[5][off];
            B3h[ni] = *(const bf16x8*)&lds[6][off];
            B3l[ni] = *(const bf16x8*)&lds[7][off];
        }
        // ---- MFMA: 48 per wave per chunk
        #pragma unroll
        for (int mi = 0; mi < 2; ++mi)
            #pragma unroll
            for (int ni = 0; ni < 2; ++ni) {
                f32x4 c1 = acc1[mi][ni];
                f32x4 c2 = acc2[mi][ni];
                c1 = __builtin_amdgcn_mfma_f32_16x16x32_bf16(A1h[mi], B3h[ni], c1, 0, 0, 0);
                c1 = __builtin_amdgcn_mfma_f32_16x16x32_bf16(A1h[mi], B3l[ni], c1, 0, 0, 0);
                c1 = __builtin_amdgcn_mfma_f32_16x16x32_bf16(A1l[mi], B3h[ni], c1, 0, 0, 0);
                c1 = __builtin_amdgcn_mfma_f32_16x16x32_bf16(A2h[mi], B2h[ni], c1, 0, 0, 0);
                c1 = __builtin_amdgcn_mfma_f32_16x16x32_bf16(A2h[mi], B2l[ni], c1, 0, 0, 0);
                c1 = __builtin_amdgcn_mfma_f32_16x16x32_bf16(A2l[mi], B2h[ni], c1, 0, 0, 0);
                c2 = __builtin_amdgcn_mfma_f32_16x16x32_bf16(A1h[mi], B2h[ni], c2, 0, 0, 0);
                c2 = __builtin_amdgcn_mfma_f32_16x16x32_bf16(A1h[mi], B2l[ni], c2, 0, 0, 0);
                c2 = __builtin_amdgcn_mfma_f32_16x16x32_bf16(A1l[mi], B2h[ni], c2, 0, 0, 0);
                c2 = __builtin_amdgcn_mfma_f32_16x16x32_bf16(A2h[mi], B3h[ni], c2, 0, 0, 0);
                c2 = __builtin_amdgcn_mfma_f32_16x16x32_bf16(A2h[mi], B3l[ni], c2, 0, 0, 0);
                c2 = __builtin_amdgcn_mfma_f32_16x16x32_bf16(A2l[mi], B3h[ni], c2, 0, 0, 0);
                acc1[mi][ni] = c1;
                acc2[mi][ni] = c2;
            }
        __syncthreads();
    }

    // ---- epilogue: C/D layout col=lane&15, row=(lane>>4)*4+reg
    const size_t DU = (size_t)D_ * U_;
    const size_t base0 = (((size_t)ts*B_ + b)*2)*DU;
    #pragma unroll
    for (int mi = 0; mi < 2; ++mi)
        #pragma unroll
        for (int ni = 0; ni < 2; ++ni) {
            const int d = d0 + 32*wd + 16*mi + 4*lg;
            const int u = 32*wu + 16*ni + lr;
            #pragma unroll
            for (int r = 0; r < 4; ++r) {
                P[base0 + (size_t)(d+r)*U_ + u]      = acc1[mi][ni][r];
                P[base0 + DU + (size_t)(d+r)*U_ + u] = acc2[mi][ni][r];
            }
        }
}

// ---------------------------------------------------------------------------
// K1b: M1 = w1 + sum_ts P[ts][b][0];  M2 = w1 + sum_ts P[ts][b][1]
// ---------------------------------------------------------------------------
__global__ __launch_bounds__(256) void k1_combine(
    const float* __restrict__ P, const float* __restrict__ w1,
    float* __restrict__ M1, float* __restrict__ M2)
{
    const int n = blockIdx.x*256 + threadIdx.x;   // 0 .. B*D*U/4-1
    const int b = n >> 13;                        // D*U/4 = 8192
    const int r = n & 8191;
    const size_t du = (size_t)r * 4;
    const size_t DU = (size_t)D_ * U_;
    float4 w = *(const float4*)&w1[du];
    float4 s1 = w, s2 = w;
    #pragma unroll
    for (int ts = 0; ts < TS_; ++ts) {
        const float* Pb = P + (((size_t)ts*B_ + b)*2)*DU + du;
        float4 a = *(const float4*)&Pb[0];
        float4 c = *(const float4*)&Pb[DU];
        s1.x += a.x; s1.y += a.y; s1.z += a.z; s1.w += a.w;
        s2.x += c.x; s2.y += c.y; s2.z += c.z; s2.w += c.w;
    }
    *(float4*)&M1[(size_t)b*DU + du] = s1;
    *(float4*)&M2[(size_t)b*DU + du] = s2;
}

// ---------------------------------------------------------------------------
// K2 (MFMA): eij[br][b][t] = SR * sum_u tanh( H[t,u] ) * we[u],
//   H = x[b] @ M[br][b]   (1024x64, K=512), bf16-split 3-term emulation.
// Block = (t-tile 64) x b x br; 4 waves, wave w owns t-rows 16w..16w+15,
// all 64 u. K staged in 64-d chunks: x as [t][d] hi/lo, M transposed to
// [u][d] hi/lo. Both tiles have 128B rows (m201 16-way-conflict geometry)
// -> XOR swizzle byte ^= (row&7)<<4 on write and read (8 lanes/slot, even).
// Epilogue: tanh + we-weighted sum per lane, 16-lane shfl_xor reduce over u.
// ---------------------------------------------------------------------------
__global__ __launch_bounds__(256, 4) void k2_eij(
    const float* __restrict__ x1, const float* __restrict__ x2,
    const float* __restrict__ M1, const float* __restrict__ M2,
    const float* __restrict__ we, float* __restrict__ eij)
{
    __shared__ ushort xh[64*64];   // 8 KiB each; 32 KiB total
    __shared__ ushort xl[64*64];
    __shared__ ushort mh[64*64];
    __shared__ ushort ml[64*64];

    const int tt = blockIdx.x;       // 0..15
    const int b  = blockIdx.y;       // 0..31
    const int br = blockIdx.z;       // 0..1
    const float* x = br ? x2 : x1;
    const float* M = (br ? M2 : M1) + (size_t)b * D_ * U_;
    const int tid  = threadIdx.x;
    const int lane = tid & 63;
    const int wid  = tid >> 6;       // wave -> t-row block (16 rows)
    const int lr   = lane & 15;
    const int lg   = lane >> 4;

    // staging decomposition
    const int s_tl = tid >> 4;       // 0..15 : t row (x stage)
    const int s_f4 = tid & 15;       // float4 col within 64-d chunk
    const int m_u  = tid & 63;       // u column (M stage)
    const int m_dq = tid >> 6;       // 0..3 : 16-d slice

    f32x4 acc[4];
    const f32x4 z = {0.f, 0.f, 0.f, 0.f};
    #pragma unroll
    for (int ni = 0; ni < 4; ++ni) acc[ni] = z;

    float wreg[4];
    #pragma unroll
    for (int ni = 0; ni < 4; ++ni) wreg[ni] = we[ni*16 + lr];

    const size_t xbase = ((size_t)b*T_ + (size_t)tt*64) * D_;

    for (int c = 0; c < D_/64; ++c) {
        const int d0 = c*64;
        // ---- x tile: [64 t][64 d] hi/lo, swizzled
        #pragma unroll
        for (int j = 0; j < 4; ++j) {
            int t = j*16 + s_tl;
            float4 v = *(const float4*)&x[xbase + (size_t)t*D_ + d0 + s_f4*4];
            float hx = hi_part(v.x), hy = hi_part(v.y), hz = hi_part(v.z), hw = hi_part(v.w);
            uint h0 = pack_hi2(v.x, v.y), h1 = pack_hi2(v.z, v.w);
            uint l0 = pack_hi2(v.x - hx, v.y - hy);
            uint l1 = pack_hi2(v.z - hz, v.w - hw);
            int cu  = s_f4*2;
            int swz = (t & 7) << 2;           // uint-granule XOR of byte-bit-4..6
            ((uint*)xh)[t*32 + ((cu  ) ^ swz)] = h0;
            ((uint*)xh)[t*32 + ((cu+1) ^ swz)] = h1;
            ((uint*)xl)[t*32 + ((cu  ) ^ swz)] = l0;
            ((uint*)xl)[t*32 + ((cu+1) ^ swz)] = l1;
        }
        // ---- M tile transposed: [64 u][64 d] hi/lo, swizzled
        {
            int swz = (m_u & 7) << 2;
            #pragma unroll
            for (int j2 = 0; j2 < 8; ++j2) {
                float e = M[(size_t)(d0 + m_dq*16 + 2*j2    )*U_ + m_u];
                float o = M[(size_t)(d0 + m_dq*16 + 2*j2 + 1)*U_ + m_u];
                float he = hi_part(e), ho = hi_part(o);
                uint hm = pack_hi2(e, o);
                uint lm = pack_hi2(e - he, o - ho);
                int cu = m_dq*8 + j2;
                ((uint*)mh)[m_u*32 + (cu ^ swz)] = hm;
                ((uint*)ml)[m_u*32 + (cu ^ swz)] = lm;
            }
        }
        __syncthreads();
        // ---- MFMA: per wave 2 kk x 4 ni x 3 = 24 per chunk
        #pragma unroll
        for (int kk = 0; kk < 2; ++kk) {
            const int ar   = wid*16 + lr;
            const int aoff = ar*64 + (((lg + 4*kk)*8) ^ ((ar & 7) << 3));
            bf16x8 Ah = *(const bf16x8*)&xh[aoff];
            bf16x8 Al = *(const bf16x8*)&xl[aoff];
            #pragma unroll
            for (int ni = 0; ni < 4; ++ni) {
                const int bu   = ni*16 + lr;
                const int boff = bu*64 + (((lg + 4*kk)*8) ^ ((bu & 7) << 3));
                bf16x8 Bh = *(const bf16x8*)&mh[boff];
                bf16x8 Bl = *(const bf16x8*)&ml[boff];
                f32x4 a = acc[ni];
                a = __builtin_amdgcn_mfma_f32_16x16x32_bf16(Ah, Bh, a, 0, 0, 0);
                a = __builtin_amdgcn_mfma_f32_16x16x32_bf16(Ah, Bl, a, 0, 0, 0);
                a = __builtin_amdgcn_mfma_f32_16x16x32_bf16(Al, Bh, a, 0, 0, 0);
                acc[ni] = a;
            }
        }
        __syncthreads();
    }

    // ---- epilogue: row=(lane>>4)*4+r, col=ni*16+lr
    #pragma unroll
    for (int r = 0; r < 4; ++r) {
        float s = 0.f;
        #pragma unroll
        for (int ni = 0; ni < 4; ++ni) s += tanhf(acc[ni][r]) * wreg[ni];
        s += __shfl_xor(s, 1);
        s += __shfl_xor(s, 2);
        s += __shfl_xor(s, 4);
        s += __shfl_xor(s, 8);
        if (lr == 0) {
            int t = tt*64 + wid*16 + lg*4 + r;
            eij[((size_t)br*B_ + b)*T_ + t] = SR_ * s;
        }
    }
}

// ---------------------------------------------------------------------------
// K45: fused softmax + scale. Each block redundantly computes the softmax
// normalization for its (br,b) slab (4 KB of eij), then scales a 64-t chunk.
//   ww = exp(e-m)/(sum + eps*exp(-m));  out[br][b,t,d] = x[b,t,d]*ww[t]
// ---------------------------------------------------------------------------
__global__ __launch_bounds__(256) void k45_scale(
    const float* __restrict__ x1, const float* __restrict__ x2,
    const float* __restrict__ eij, float* __restrict__ out)
{
    __shared__ float sdata[256];
    __shared__ float wws[T_];

    const int tt = blockIdx.x;       // 0..15 : t-chunk of 64
    const int b  = blockIdx.y;       // 0..31
    const int br = blockIdx.z;       // 0..1
    const int tid = threadIdx.x;
    const float* e = eij + ((size_t)br*B_ + b) * T_;

    float v[4];
    float m = -1e30f;
    #pragma unroll
    for (int i = 0; i < 4; ++i) { v[i] = e[tid + i*256]; m = fmaxf(m, v[i]); }
    sdata[tid] = m; __syncthreads();
    for (int s = 128; s > 0; s >>= 1) {
        if (tid < s) sdata[tid] = fmaxf(sdata[tid], sdata[tid+s]);
        __syncthreads();
    }
    m = sdata[0]; __syncthreads();
    float ssum = 0.f;
    #pragma unroll
    for (int i = 0; i < 4; ++i) { v[i] = expf(v[i] - m); ssum += v[i]; }
    sdata[tid] = ssum; __syncthreads();
    for (int s = 128; s > 0; s >>= 1) {
        if (tid < s) sdata[tid] += sdata[tid+s];
        __syncthreads();
    }
    const float inv = 1.0f / (sdata[0] + EPS_ * expf(-m));
    #pragma unroll
    for (int i = 0; i < 4; ++i) wws[tid + i*256] = v[i] * inv;
    __syncthreads();

    // scale: t in [tt*64, tt*64+64), all d. 64*128 float4 = 8192; 32/thread.
    const float* x = br ? x2 : x1;
    const size_t xb4 = ((size_t)b*T_ + (size_t)tt*64) * (D_/4);
    float* o = out + (size_t)br*B_*T_*D_;
    #pragma unroll
    for (int k = 0; k < 32; ++k) {
        int idx = k*256 + tid;           // 0..8191
        int tl  = idx >> 7;              // 0..63 (128 float4 per t-row)
        float w = wws[tt*64 + tl];
        float4 xv = ((const float4*)x)[xb4 + idx];
        float4 ov = {xv.x*w, xv.y*w, xv.z*w, xv.w*w};
        ((float4*)o)[xb4 + idx] = ov;
    }
}

// ---------------------------------------------------------------------------
extern "C" void kernel_launch(void* const* d_in, const int* in_sizes, int n_in,
                              void* d_out, int out_size, void* d_ws, size_t ws_size,
                              hipStream_t stream)
{
    const float* x1 = (const float*)d_in[0];
    const float* x2 = (const float*)d_in[1];
    const float* w1 = (const float*)d_in[2];
    const float* w2 = (const float*)d_in[3];
    const float* w3 = (const float*)d_in[4];
    const float* we = (const float*)d_in[5];
    float* out = (float*)d_out;
    float* ws  = (float*)d_ws;

    // workspace layout (floats)
    float* P   = ws;                             // TS_*B_*2*D_*U_ = 8,388,608
    float* M1  = P   + (size_t)TS_*B_*2*D_*U_;   // 1,048,576
    float* M2  = M1  + (size_t)B_*D_*U_;         // 1,048,576
    float* eij = M2  + (size_t)B_*D_*U_;         // 65,536

    k1_partials<<<dim3(8, TS_, B_), 256, 0, stream>>>(x1, x2, w2, w3, P);
    k1_combine <<<dim3((B_*D_*U_/4 + 255)/256), 256, 0, stream>>>(P, w1, M1, M2);
    k2_eij     <<<dim3(T_/TT_, B_, 2), 256, 0, stream>>>(x1, x2, M1, M2, we, eij);
    k45_scale  <<<dim3(16, B_, 2), 256, 0, stream>>>(x1, x2, eij, out);
}